// Round 8
// baseline (761.414 us; speedup 1.0000x reference)
//
#include <hip/hip_runtime.h>
#include <hip/hip_cooperative_groups.h>
#include <math.h>

namespace cg = cooperative_groups;

#pragma clang fp contract(off)

#define BN 4
#define SX 512
#define SY 512
#define NPIX (BN * SX * SY)
#define MU 5
#define MB (1024 * 1024)
#define GRID_BLKS 512    // 2 blocks/CU guaranteed by __launch_bounds__(256,2)
#define NBLOCKS 2048     // fallback path partials

struct DogW  { float g[7];  float tw; };
struct FdogW { float g[10]; float tw; };

// tanh via expm1 identity: tanh(d) = expm1(2|d|) / (expm1(2|d|) + 2), odd.
__device__ __forceinline__ float fast_tanh_f32(float dF) {
    double d = (double)dF;
    double y = fabs(d);
    double t = expm1(2.0 * y);
    double r = t / (t + 2.0);
    if (y > 350.0) r = 1.0;
    return (float)copysign(r, d);
}

__device__ __forceinline__ float img_at(const float* __restrict__ img, int b, int x, int y) {
    if (x < 0 || x >= SX || y < 0 || y >= SY) return 0.0f;
    return img[(size_t)b * SX * SY + (size_t)x * SY + y];
}

// ===================== fused cooperative pipeline =====================
__global__ __launch_bounds__(256, 2) void k_fused(
    const float* __restrict__ img, float* __restrict__ mag,
    float2* __restrict__ tA, float2* __restrict__ tB,
    float* __restrict__ TV, float* __restrict__ TH,
    float* __restrict__ partial, float* __restrict__ dogbuf,
    int* __restrict__ out, DogW dw, FdogW fw)
{
#pragma clang fp contract(off)
    cg::grid_group grid = cg::this_grid();
    const int tid = (int)threadIdx.x;
    const int nthreads = (int)gridDim.x * 256;
    const int gid0 = (int)blockIdx.x * 256 + tid;

    __shared__ float red[4];
    __shared__ float smax;
    const int lane = tid & 63;
    const int wid  = tid >> 6;

    // ---- Stage 1: Sobel -> mag, initial tangent (tA), per-block max ----
    float bmax = 0.0f;
    for (int id = gid0; id < NPIX; id += nthreads) {
        int yi = id & (SY - 1);
        int xi = (id >> 9) & (SX - 1);
        int b  = id >> 18;

        float v00 = img_at(img, b, xi - 1, yi - 1);
        float v01 = img_at(img, b, xi - 1, yi    );
        float v02 = img_at(img, b, xi - 1, yi + 1);
        float v10 = img_at(img, b, xi,     yi - 1);
        float v12 = img_at(img, b, xi,     yi + 1);
        float v20 = img_at(img, b, xi + 1, yi - 1);
        float v21 = img_at(img, b, xi + 1, yi    );
        float v22 = img_at(img, b, xi + 1, yi + 1);

        float s0 = (-1.0f * v00);
        s0 = s0 + (-2.0f * v01);
        s0 = s0 + (-1.0f * v02);
        s0 = s0 + ( 1.0f * v20);
        s0 = s0 + ( 2.0f * v21);
        s0 = s0 + ( 1.0f * v22);
        float s1 = (-1.0f * v00);
        s1 = s1 + ( 1.0f * v02);
        s1 = s1 + (-2.0f * v10);
        s1 = s1 + ( 2.0f * v12);
        s1 = s1 + (-1.0f * v20);
        s1 = s1 + ( 1.0f * v22);

        float m = sqrtf((s0 * s0) + (s1 * s1));
        mag[id] = m;

        float tx = -s1, ty = s0;
        float n = sqrtf((tx * tx) + (ty * ty));
        float d = (n == 0.0f) ? 1.0f : n;
        tA[id] = make_float2(tx / d, ty / d);
        bmax = fmaxf(bmax, m);
    }
    for (int off = 32; off > 0; off >>= 1) bmax = fmaxf(bmax, __shfl_down(bmax, off, 64));
    if (lane == 0) red[wid] = bmax;
    __syncthreads();
    if (tid == 0) partial[blockIdx.x] = fmaxf(fmaxf(red[0], red[1]), fmaxf(red[2], red[3]));
    grid.sync();   // S1: mag, tA, partial visible

    // ---- every block redundantly reduces the global max (no extra sync) ----
    {
        float m = 0.0f;
        for (int i = tid; i < (int)gridDim.x; i += 256) m = fmaxf(m, partial[i]);
        for (int off = 32; off > 0; off >>= 1) m = fmaxf(m, __shfl_down(m, off, 64));
        if (lane == 0) red[wid] = m;
        __syncthreads();
        if (tid == 0) smax = fmaxf(fmaxf(red[0], red[1]), fmaxf(red[2], red[3]));
        __syncthreads();
    }
    const float mx = smax;

    // ---- Stage 2: tanh difference fields (normalization fused, exact) ----
    for (int id = gid0; id < NPIX; id += nthreads) {
        int yi = id & (SY - 1);
        int xi = (id >> 9) & (SX - 1);
        float cm = mag[id] / mx;
#pragma unroll
        for (int k = 1; k <= 5; ++k) {
            if (xi + k < SX) {
                float nm = mag[id + k * SY] / mx;
                TV[(size_t)(k - 1) * NPIX + id] = fast_tanh_f32(nm - cm);
            }
        }
#pragma unroll
        for (int k = 1; k <= 5; ++k) {
            if (yi + k < SY) {
                float nm = mag[id + k] / mx;
                TH[(size_t)(k - 1) * NPIX + id] = fast_tanh_f32(nm - cm);
            }
        }
    }
    grid.sync();   // S2: TV, TH visible

    // ---- Stage 3: 3 x (V pass, H pass); dog fused into the last H pass ----
    float2* src = tA;
    float2* dst = tB;
    for (int it = 0; it < 3; ++it) {
        // V pass
        for (int id = gid0; id < NPIX; id += nthreads) {
            int xi = (id >> 9) & (SX - 1);
            float2 ct = src[id];
            float sx = 0.0f, sy = 0.0f;
#pragma unroll
            for (int k = -MU; k <= MU; ++k) {
                int nx = xi + k;
                if (nx < 0 || nx >= SX) continue;
                int nidx = id + k * SY;
                float2 nt = src[nidx];
                float th;
                if (k > 0)      th =  TV[(size_t)(k - 1) * NPIX + id];
                else if (k < 0) th = -TV[(size_t)(-k - 1) * NPIX + nidx];
                else            th =  0.0f;
                float dot = (ct.x * nt.x) + (ct.y * nt.y);
                float w   = ((th + 1.0f) * dot) * 0.5f;
                sx = sx + (nt.x * w);
                sy = sy + (nt.y * w);
            }
            float n = sqrtf((sx * sx) + (sy * sy));
            float d = (n == 0.0f) ? 1.0f : n;
            dst[id] = make_float2(sx / d, sy / d);
        }
        grid.sync();
        { float2* t = src; src = dst; dst = t; }

        // H pass (+ dog on last iteration)
        bool last = (it == 2);
        for (int id = gid0; id < NPIX; id += nthreads) {
            int yi = id & (SY - 1);
            float2 ct = src[id];
            float sx = 0.0f, sy = 0.0f;
#pragma unroll
            for (int k = -MU; k <= MU; ++k) {
                int ny = yi + k;
                if (ny < 0 || ny >= SY) continue;
                int nidx = id + k;
                float2 nt = src[nidx];
                float th;
                if (k > 0)      th =  TH[(size_t)(k - 1) * NPIX + id];
                else if (k < 0) th = -TH[(size_t)(-k - 1) * NPIX + nidx];
                else            th =  0.0f;
                float dot = (ct.x * nt.x) + (ct.y * nt.y);
                float w   = ((th + 1.0f) * dot) * 0.5f;
                sx = sx + (nt.x * w);
                sy = sy + (nt.y * w);
            }
            float n = sqrtf((sx * sx) + (sy * sy));
            float d = (n == 0.0f) ? 1.0f : n;
            float ex = sx / d, ey = sy / d;
            dst[id] = make_float2(ex, ey);

            if (last) {
                // dog is per-pixel in the final etf: use the just-computed value
                int xi = (id >> 9) & (SX - 1);
                int b  = id >> 18;
                size_t base = (size_t)b << 18;
                float perx = -ey, pery = ex;
                float xf = (float)xi, yf = (float)yi;
                float acc = 0.0f;
#pragma unroll
                for (int t = -3; t <= 3; ++t) {
                    float tf  = (float)t;
                    float ptx = xf + (perx * tf);
                    float pty = yf + (pery * tf);
                    int px = (int)rintf(fminf(fmaxf(ptx, 0.0f), (float)(SX - 1)));
                    int py = (int)rintf(fminf(fmaxf(pty, 0.0f), (float)(SY - 1)));
                    float il = img[base + (size_t)px * SY + py];
                    acc = acc + (il * dw.g[t + 3]);
                }
                dogbuf[id] = acc / dw.tw;
            }
        }
        grid.sync();
        { float2* t = src; src = dst; dst = t; }
    }
    // final etf in src (== tA); dog in dogbuf — both visible after the last sync.

    // ---- Stage 5: FDoG dual-chain trace + threshold ----
    const float2* etf = src;
    for (int id = gid0; id < NPIX; id += nthreads) {
        int yi = id & (SY - 1);
        int xi = (id >> 9) & (SX - 1);
        int b  = id >> 18;
        size_t base = (size_t)b << 18;

        float d1[9];
        float d2[10];
        float2 e0 = etf[id];
        float2 e1 = e0, e2 = e0;
        int p1x = xi, p1y = yi;
        int p2x = xi, p2y = yi;
        d2[0] = dogbuf[id];

#pragma unroll
        for (int s = 1; s <= 9; ++s) {
            float fx1 = (float)p1x + (e1.x * -1.0f);
            float fy1 = (float)p1y + (e1.y * -1.0f);
            p1x = (int)rintf(fminf(fmaxf(fx1, 0.0f), (float)(SX - 1)));
            p1y = (int)rintf(fminf(fmaxf(fy1, 0.0f), (float)(SY - 1)));
            size_t i1 = base + (size_t)p1x * SY + p1y;
            float fx2 = (float)p2x + (e2.x * 1.0f);
            float fy2 = (float)p2y + (e2.y * 1.0f);
            p2x = (int)rintf(fminf(fmaxf(fx2, 0.0f), (float)(SX - 1)));
            p2y = (int)rintf(fminf(fmaxf(fy2, 0.0f), (float)(SY - 1)));
            size_t i2 = base + (size_t)p2x * SY + p2y;

            d1[s - 1] = dogbuf[i1];
            d2[s]     = dogbuf[i2];
            if (s < 9) {
                e1 = etf[i1];
                e2 = etf[i2];
            }
        }

        float acc = 0.0f;
#pragma unroll
        for (int s = 1; s <= 9; ++s) acc = acc + (d1[s - 1] * fw.g[s]);
        acc = acc + (d2[0] * fw.g[0]);
#pragma unroll
        for (int s = 1; s <= 9; ++s) acc = acc + (d2[s] * fw.g[s]);

        float fv = acc / fw.tw;
        float th = 1.0f + fast_tanh_f32(fv);
        out[id] = ((fv < 0.0f) && (th < 0.7f)) ? 0 : 1;
    }
}

// ===================== fallback (multi-kernel, proven R5) =====================
#define SLAB_DECODE                                   \
    int slab = blockIdx.x;                            \
    int b    = slab >> 1;                             \
    int xi   = ((slab & 1) << 8) + blockIdx.y;        \
    size_t base = (size_t)b * SX * SY;                \
    size_t rowb = base + (size_t)xi * SY;

__global__ __launch_bounds__(256) void k_sobel(const float* __restrict__ img,
                                               float* __restrict__ mag,
                                               float2* __restrict__ tang,
                                               float* __restrict__ partial) {
#pragma clang fp contract(off)
    SLAB_DECODE
    float bmax = 0.0f;
#pragma unroll
    for (int half = 0; half < 2; ++half) {
        int yi = (int)threadIdx.x + half * 256;
        float v00 = img_at(img, b, xi - 1, yi - 1);
        float v01 = img_at(img, b, xi - 1, yi    );
        float v02 = img_at(img, b, xi - 1, yi + 1);
        float v10 = img_at(img, b, xi,     yi - 1);
        float v12 = img_at(img, b, xi,     yi + 1);
        float v20 = img_at(img, b, xi + 1, yi - 1);
        float v21 = img_at(img, b, xi + 1, yi    );
        float v22 = img_at(img, b, xi + 1, yi + 1);
        float s0 = (-1.0f * v00);
        s0 = s0 + (-2.0f * v01);
        s0 = s0 + (-1.0f * v02);
        s0 = s0 + ( 1.0f * v20);
        s0 = s0 + ( 2.0f * v21);
        s0 = s0 + ( 1.0f * v22);
        float s1 = (-1.0f * v00);
        s1 = s1 + ( 1.0f * v02);
        s1 = s1 + (-2.0f * v10);
        s1 = s1 + ( 2.0f * v12);
        s1 = s1 + (-1.0f * v20);
        s1 = s1 + ( 1.0f * v22);
        float m = sqrtf((s0 * s0) + (s1 * s1));
        mag[rowb + yi] = m;
        float tx = -s1, ty = s0;
        float n = sqrtf((tx * tx) + (ty * ty));
        float d = (n == 0.0f) ? 1.0f : n;
        tang[rowb + yi] = make_float2(tx / d, ty / d);
        bmax = fmaxf(bmax, m);
    }
    for (int off = 32; off > 0; off >>= 1) bmax = fmaxf(bmax, __shfl_down(bmax, off, 64));
    __shared__ float red[4];
    int lane = threadIdx.x & 63;
    int wid  = threadIdx.x >> 6;
    if (lane == 0) red[wid] = bmax;
    __syncthreads();
    if (threadIdx.x == 0) {
        partial[blockIdx.x + 8 * blockIdx.y] =
            fmaxf(fmaxf(red[0], red[1]), fmaxf(red[2], red[3]));
    }
}

__global__ void k_reduce(const float* __restrict__ partial, unsigned int* __restrict__ maxbits) {
    float m = 0.0f;
    for (int i = threadIdx.x; i < NBLOCKS; i += 256) m = fmaxf(m, partial[i]);
    for (int off = 32; off > 0; off >>= 1) m = fmaxf(m, __shfl_down(m, off, 64));
    __shared__ float red[4];
    int lane = threadIdx.x & 63;
    int wid  = threadIdx.x >> 6;
    if (lane == 0) red[wid] = m;
    __syncthreads();
    if (threadIdx.x == 0)
        *maxbits = __float_as_uint(fmaxf(fmaxf(red[0], red[1]), fmaxf(red[2], red[3])));
}

__global__ __launch_bounds__(256) void k_tanh(const float* __restrict__ mag,
                                              const unsigned int* __restrict__ maxbits,
                                              float* __restrict__ TV, float* __restrict__ TH) {
#pragma clang fp contract(off)
    SLAB_DECODE
    float mx = __uint_as_float(*maxbits);
#pragma unroll
    for (int half = 0; half < 2; ++half) {
        int yi = (int)threadIdx.x + half * 256;
        size_t idx = rowb + yi;
        float cm = mag[idx] / mx;
#pragma unroll
        for (int k = 1; k <= 5; ++k) {
            if (xi + k < SX) {
                float nm = mag[idx + (size_t)k * SY] / mx;
                TV[(size_t)(k - 1) * NPIX + idx] = fast_tanh_f32(nm - cm);
            }
        }
#pragma unroll
        for (int k = 1; k <= 5; ++k) {
            if (yi + k < SY) {
                float nm = mag[idx + k] / mx;
                TH[(size_t)(k - 1) * NPIX + idx] = fast_tanh_f32(nm - cm);
            }
        }
    }
}

__global__ __launch_bounds__(256) void k_etf_v(const float2* __restrict__ tsrc,
                                               float2* __restrict__ tdst,
                                               const float* __restrict__ TV) {
#pragma clang fp contract(off)
    SLAB_DECODE
#pragma unroll
    for (int half = 0; half < 2; ++half) {
        int yi = (int)threadIdx.x + half * 256;
        size_t idx = rowb + yi;
        float2 ct = tsrc[idx];
        float sx = 0.0f, sy = 0.0f;
#pragma unroll
        for (int k = -MU; k <= MU; ++k) {
            int nx = xi + k;
            if (nx < 0 || nx >= SX) continue;
            size_t nidx = idx + (size_t)k * SY;
            float2 nt = tsrc[nidx];
            float th;
            if (k > 0)      th =  TV[(size_t)(k - 1) * NPIX + idx];
            else if (k < 0) th = -TV[(size_t)(-k - 1) * NPIX + nidx];
            else            th =  0.0f;
            float dot = (ct.x * nt.x) + (ct.y * nt.y);
            float w   = ((th + 1.0f) * dot) * 0.5f;
            sx = sx + (nt.x * w);
            sy = sy + (nt.y * w);
        }
        float n = sqrtf((sx * sx) + (sy * sy));
        float d = (n == 0.0f) ? 1.0f : n;
        tdst[idx] = make_float2(sx / d, sy / d);
    }
}

__global__ __launch_bounds__(256) void k_etf_h(const float2* __restrict__ tsrc,
                                               float2* __restrict__ tdst,
                                               const float* __restrict__ TH) {
#pragma clang fp contract(off)
    SLAB_DECODE
    int tid = threadIdx.x;

    __shared__ __align__(16) float2 sT[SY];
    __shared__ __align__(16) float  sTH[5][SY];

    ((float4*)sT)[tid] = ((const float4*)(tsrc + rowb))[tid];
    for (int i = tid; i < 5 * (SY / 4); i += 256) {
        int j = i >> 7;
        int c = i & 127;
        ((float4*)&sTH[0][0])[i] = ((const float4*)(TH + (size_t)j * NPIX + rowb))[c];
    }
    __syncthreads();

#pragma unroll
    for (int half = 0; half < 2; ++half) {
        int yi = tid + half * 256;
        float2 ct = sT[yi];
        float sx = 0.0f, sy = 0.0f;
#pragma unroll
        for (int k = -MU; k <= MU; ++k) {
            int ny = yi + k;
            if (ny < 0 || ny >= SY) continue;
            float2 nt = sT[ny];
            float th;
            if (k > 0)      th =  sTH[k - 1][yi];
            else if (k < 0) th = -sTH[-k - 1][ny];
            else            th =  0.0f;
            float dot = (ct.x * nt.x) + (ct.y * nt.y);
            float w   = ((th + 1.0f) * dot) * 0.5f;
            sx = sx + (nt.x * w);
            sy = sy + (nt.y * w);
        }
        float n = sqrtf((sx * sx) + (sy * sy));
        float d = (n == 0.0f) ? 1.0f : n;
        tdst[rowb + yi] = make_float2(sx / d, sy / d);
    }
}

__global__ __launch_bounds__(256) void k_dog(const float* __restrict__ img,
                                             const float2* __restrict__ etf,
                                             float* __restrict__ dog, DogW w) {
#pragma clang fp contract(off)
    SLAB_DECODE
#pragma unroll
    for (int half = 0; half < 2; ++half) {
        int yi = (int)threadIdx.x + half * 256;
        size_t idx = rowb + yi;
        float2 e = etf[idx];
        float perx = -e.y;
        float pery =  e.x;
        float xf = (float)xi, yf = (float)yi;
        float acc = 0.0f;
#pragma unroll
        for (int t = -3; t <= 3; ++t) {
            float tf  = (float)t;
            float ptx = xf + (perx * tf);
            float pty = yf + (pery * tf);
            int px = (int)rintf(fminf(fmaxf(ptx, 0.0f), (float)(SX - 1)));
            int py = (int)rintf(fminf(fmaxf(pty, 0.0f), (float)(SY - 1)));
            float il = img[base + (size_t)px * SY + py];
            acc = acc + (il * w.g[t + 3]);
        }
        dog[idx] = acc / w.tw;
    }
}

__global__ __launch_bounds__(256) void k_fdog(const float* __restrict__ dog,
                                              const float2* __restrict__ etf,
                                              int* __restrict__ out, FdogW w) {
#pragma clang fp contract(off)
    SLAB_DECODE
    for (int half = 0; half < 2; ++half) {
        int yi = (int)threadIdx.x + half * 256;
        size_t idx = rowb + yi;
        float d1[9];
        float d2[10];
        float2 e0 = etf[idx];
        float2 e1 = e0, e2 = e0;
        int p1x = xi, p1y = yi;
        int p2x = xi, p2y = yi;
        d2[0] = dog[idx];
#pragma unroll
        for (int s = 1; s <= 9; ++s) {
            float fx1 = (float)p1x + (e1.x * -1.0f);
            float fy1 = (float)p1y + (e1.y * -1.0f);
            p1x = (int)rintf(fminf(fmaxf(fx1, 0.0f), (float)(SX - 1)));
            p1y = (int)rintf(fminf(fmaxf(fy1, 0.0f), (float)(SY - 1)));
            size_t i1 = base + (size_t)p1x * SY + p1y;
            float fx2 = (float)p2x + (e2.x * 1.0f);
            float fy2 = (float)p2y + (e2.y * 1.0f);
            p2x = (int)rintf(fminf(fmaxf(fx2, 0.0f), (float)(SX - 1)));
            p2y = (int)rintf(fminf(fmaxf(fy2, 0.0f), (float)(SY - 1)));
            size_t i2 = base + (size_t)p2x * SY + p2y;
            d1[s - 1] = dog[i1];
            d2[s]     = dog[i2];
            if (s < 9) {
                e1 = etf[i1];
                e2 = etf[i2];
            }
        }
        float acc = 0.0f;
#pragma unroll
        for (int s = 1; s <= 9; ++s) acc = acc + (d1[s - 1] * w.g[s]);
        acc = acc + (d2[0] * w.g[0]);
#pragma unroll
        for (int s = 1; s <= 9; ++s) acc = acc + (d2[s] * w.g[s]);
        float fv = acc / w.tw;
        float th = 1.0f + fast_tanh_f32(fv);
        out[idx] = ((fv < 0.0f) && (th < 0.7f)) ? 0 : 1;
    }
}

static double gpdf(double v, double sig) {
    return exp(-(v * v) / (2.0 * sig * sig)) / (sqrt(2.0 * M_PI) * sig);
}

extern "C" void kernel_launch(void* const* d_in, const int* in_sizes, int n_in,
                              void* d_out, int out_size, void* d_ws, size_t ws_size,
                              hipStream_t stream) {
    const float* img = (const float*)d_in[0];
    int* out = (int*)d_out;
    char* ws = (char*)d_ws;

    // Workspace layout (64 MB + 8 KB + 4 B):
    //   mag [0,4MB) | tA [4,12) | tB [12,20) | TV [20,40) | TH [40,60) | dog [60,64)
    //   partial [64MB, +8KB) | maxbits [+4)
    const size_t need = (size_t)64 * MB + NBLOCKS * sizeof(float) + 4;
    (void)need;

    float*  mag = (float*)(ws);
    float2* tA  = (float2*)(ws + (size_t)4  * MB);
    float2* tB  = (float2*)(ws + (size_t)12 * MB);
    float*  TV  = (float*)(ws + (size_t)20 * MB);
    float*  TH  = (float*)(ws + (size_t)40 * MB);
    float*  dog = (float*)(ws + (size_t)60 * MB);
    float*        partial = (float*)(ws + (size_t)64 * MB);
    unsigned int* maxbits = (unsigned int*)(ws + (size_t)64 * MB + NBLOCKS * sizeof(float));

    DogW dw;
    {
        double tw = 0.0;
        for (int t = -3; t <= 3; ++t) {
            double g = gpdf((double)t, 1.0) - 0.99 * gpdf((double)t, 1.6);
            dw.g[t + 3] = (float)g;
            tw += g;
        }
        dw.tw = (float)tw;
    }
    FdogW fw;
    {
        for (int s = 0; s <= 9; ++s) fw.g[s] = (float)gpdf((double)s, 3.0);
        double tw = 0.0;
        for (int s = 1; s <= 9; ++s) tw += gpdf((double)s, 3.0);
        for (int s = 0; s <= 9; ++s) tw += gpdf((double)s, 3.0);
        fw.tw = (float)tw;
    }

    // ---- attempt single fused cooperative launch ----
    {
        void* args[] = { (void*)&img, (void*)&mag, (void*)&tA, (void*)&tB,
                         (void*)&TV, (void*)&TH, (void*)&partial, (void*)&dog,
                         (void*)&out, (void*)&dw, (void*)&fw };
        hipError_t err = hipLaunchCooperativeKernel((const void*)k_fused,
                                                    dim3(GRID_BLKS), dim3(256),
                                                    args, 0, stream);
        if (err == hipSuccess) return;
        (void)hipGetLastError();   // clear sticky error; fall through to proven path
    }

    // ---- fallback: proven multi-kernel pipeline (absmax 0.0) ----
    dim3 blk(256, 1, 1);
    dim3 sgrd(8, 256, 1);

    k_sobel<<<sgrd, blk, 0, stream>>>(img, mag, tA, partial);
    k_reduce<<<1, 256, 0, stream>>>(partial, maxbits);
    k_tanh<<<sgrd, blk, 0, stream>>>(mag, maxbits, TV, TH);

    float2* src = tA;
    float2* dst = tB;
    for (int it = 0; it < 3; ++it) {
        k_etf_v<<<sgrd, blk, 0, stream>>>(src, dst, TV);
        { float2* t = src; src = dst; dst = t; }
        k_etf_h<<<sgrd, blk, 0, stream>>>(src, dst, TH);
        { float2* t = src; src = dst; dst = t; }
    }
    k_dog<<<sgrd, blk, 0, stream>>>(img, src, dog, dw);
    k_fdog<<<sgrd, blk, 0, stream>>>(dog, src, out, fw);
}

// Round 9
// 201.453 us; speedup vs baseline: 3.7796x; 3.7796x over previous
//
#include <hip/hip_runtime.h>
#include <math.h>

#pragma clang fp contract(off)

#define BN 4
#define SX 512
#define SY 512
#define NPIX (BN * SX * SY)
#define MU 5
#define MB (1024 * 1024)
#define NBLOCKS 4096   // (SY/256) * SX * BN

struct DogW  { float g[7];  float tw; };
struct FdogW { float g[10]; float tw; };

// tanh via expm1 identity: tanh(d) = expm1(2|d|) / (expm1(2|d|) + 2), odd.
__device__ __forceinline__ float fast_tanh_f32(float dF) {
    double d = (double)dF;
    double y = fabs(d);
    double t = expm1(2.0 * y);
    double r = t / (t + 2.0);
    if (y > 350.0) r = 1.0;
    return (float)copysign(r, d);
}

__device__ __forceinline__ int clampi(int v, int lo, int hi) {
    return v < lo ? lo : (v > hi ? hi : v);
}

// Stage 1: Sobel -> mag, tangent, per-block max. All 8 halo loads are
// UNCONDITIONAL at clamped addresses (one clause), zero-selected after —
// identical values to zero-padded conv.
__global__ __launch_bounds__(256) void k_sobel(const float* __restrict__ img,
                                               float* __restrict__ mag,
                                               float2* __restrict__ tang,
                                               float* __restrict__ partial) {
#pragma clang fp contract(off)
    int yi = blockIdx.x * blockDim.x + threadIdx.x;
    int xi = blockIdx.y;
    int b  = blockIdx.z;
    size_t base = (size_t)b * SX * SY;

    int xm = clampi(xi - 1, 0, SX - 1), xp = clampi(xi + 1, 0, SX - 1);
    int ym = clampi(yi - 1, 0, SY - 1), yp = clampi(yi + 1, 0, SY - 1);
    // unconditional loads (clause-friendly)
    float l00 = img[base + (size_t)xm * SY + ym];
    float l01 = img[base + (size_t)xm * SY + yi];
    float l02 = img[base + (size_t)xm * SY + yp];
    float l10 = img[base + (size_t)xi * SY + ym];
    float l12 = img[base + (size_t)xi * SY + yp];
    float l20 = img[base + (size_t)xp * SY + ym];
    float l21 = img[base + (size_t)xp * SY + yi];
    float l22 = img[base + (size_t)xp * SY + yp];
    bool vxm = (xi - 1) >= 0, vxp = (xi + 1) < SX;
    bool vym = (yi - 1) >= 0, vyp = (yi + 1) < SY;
    float v00 = (vxm && vym) ? l00 : 0.0f;
    float v01 = (vxm       ) ? l01 : 0.0f;
    float v02 = (vxm && vyp) ? l02 : 0.0f;
    float v10 = (       vym) ? l10 : 0.0f;
    float v12 = (       vyp) ? l12 : 0.0f;
    float v20 = (vxp && vym) ? l20 : 0.0f;
    float v21 = (vxp       ) ? l21 : 0.0f;
    float v22 = (vxp && vyp) ? l22 : 0.0f;

    float s0 = (-1.0f * v00);
    s0 = s0 + (-2.0f * v01);
    s0 = s0 + (-1.0f * v02);
    s0 = s0 + ( 1.0f * v20);
    s0 = s0 + ( 2.0f * v21);
    s0 = s0 + ( 1.0f * v22);
    float s1 = (-1.0f * v00);
    s1 = s1 + ( 1.0f * v02);
    s1 = s1 + (-2.0f * v10);
    s1 = s1 + ( 2.0f * v12);
    s1 = s1 + (-1.0f * v20);
    s1 = s1 + ( 1.0f * v22);

    float m = sqrtf((s0 * s0) + (s1 * s1));
    size_t idx = base + (size_t)xi * SY + yi;
    mag[idx] = m;

    float tx = -s1, ty = s0;
    float n = sqrtf((tx * tx) + (ty * ty));
    float d = (n == 0.0f) ? 1.0f : n;
    tang[idx] = make_float2(tx / d, ty / d);

    float wm = m;
    for (int off = 32; off > 0; off >>= 1) wm = fmaxf(wm, __shfl_down(wm, off, 64));
    __shared__ float red[4];
    int lane = threadIdx.x & 63;
    int wid  = threadIdx.x >> 6;
    if (lane == 0) red[wid] = wm;
    __syncthreads();
    if (threadIdx.x == 0) {
        float bm = fmaxf(fmaxf(red[0], red[1]), fmaxf(red[2], red[3]));
        int bid = blockIdx.x + gridDim.x * (blockIdx.y + gridDim.y * blockIdx.z);
        partial[bid] = bm;
    }
}

__global__ void k_reduce(const float* __restrict__ partial, unsigned int* __restrict__ maxbits) {
    float m = 0.0f;
    for (int i = threadIdx.x; i < NBLOCKS; i += 256) m = fmaxf(m, partial[i]);
    for (int off = 32; off > 0; off >>= 1) m = fmaxf(m, __shfl_down(m, off, 64));
    __shared__ float red[4];
    int lane = threadIdx.x & 63;
    int wid  = threadIdx.x >> 6;
    if (lane == 0) red[wid] = m;
    __syncthreads();
    if (threadIdx.x == 0)
        *maxbits = __float_as_uint(fmaxf(fmaxf(red[0], red[1]), fmaxf(red[2], red[3])));
}

// Stage 2: tanh difference fields, normalization fused. 11 unconditional
// clamped loads in one clause; stores remain guarded (stores don't serialize).
__global__ __launch_bounds__(256) void k_tanh(const float* __restrict__ mag,
                                              const unsigned int* __restrict__ maxbits,
                                              float* __restrict__ TV, float* __restrict__ TH) {
#pragma clang fp contract(off)
    int yi = blockIdx.x * blockDim.x + threadIdx.x;
    int xi = blockIdx.y;
    int b  = blockIdx.z;
    size_t base = (size_t)b * SX * SY;
    size_t idx  = base + (size_t)xi * SY + yi;
    float mx = __uint_as_float(*maxbits);

    float mv[5], mh[5];
#pragma unroll
    for (int k = 1; k <= 5; ++k)
        mv[k - 1] = mag[base + (size_t)clampi(xi + k, 0, SX - 1) * SY + yi];
#pragma unroll
    for (int k = 1; k <= 5; ++k)
        mh[k - 1] = mag[base + (size_t)xi * SY + clampi(yi + k, 0, SY - 1)];
    float cm = mag[idx] / mx;

#pragma unroll
    for (int k = 1; k <= 5; ++k) {
        if (xi + k < SX)
            TV[(size_t)(k - 1) * NPIX + idx] = fast_tanh_f32((mv[k - 1] / mx) - cm);
    }
#pragma unroll
    for (int k = 1; k <= 5; ++k) {
        if (yi + k < SY)
            TH[(size_t)(k - 1) * NPIX + idx] = fast_tanh_f32((mh[k - 1] / mx) - cm);
    }
}

// Stage 3a: V-pass. 11 tap + 10 T loads, all unconditional at clamped
// addresses (one deep clause), validity applied as selects afterward.
// Invalid taps -> nt=(0,0), th=0: contribution is the reference's
// zero-padded ±0 — bit-exact.
__global__ __launch_bounds__(256) void k_etf_v(const float2* __restrict__ tsrc,
                                               float2* __restrict__ tdst,
                                               const float* __restrict__ TV) {
#pragma clang fp contract(off)
    int yi = blockIdx.x * blockDim.x + threadIdx.x;
    int xi = blockIdx.y;
    int b  = blockIdx.z;
    size_t base = (size_t)b * SX * SY;
    size_t idx  = base + (size_t)xi * SY + yi;

    float2 nt[11];
    float  tv[11];
#pragma unroll
    for (int k = -MU; k <= MU; ++k) {
        int nxc = clampi(xi + k, 0, SX - 1);
        nt[k + MU] = tsrc[base + (size_t)nxc * SY + yi];
        if (k > 0)      tv[k + MU] = TV[(size_t)(k - 1) * NPIX + idx];
        else if (k < 0) tv[k + MU] = TV[(size_t)(-k - 1) * NPIX + base + (size_t)nxc * SY + yi];
        else            tv[k + MU] = 0.0f;
    }
    float2 ct = nt[MU];

    float sx = 0.0f, sy = 0.0f;
#pragma unroll
    for (int k = -MU; k <= MU; ++k) {
        bool valid = ((unsigned)(xi + k)) < (unsigned)SX;
        float2 v = nt[k + MU];
        float vx = valid ? v.x : 0.0f;
        float vy = valid ? v.y : 0.0f;
        float th;
        if (k > 0)      th = valid ?  tv[k + MU] : 0.0f;
        else if (k < 0) th = valid ? -tv[k + MU] : 0.0f;
        else            th = 0.0f;
        float dot = (ct.x * vx) + (ct.y * vy);
        float w   = ((th + 1.0f) * dot) * 0.5f;
        sx = sx + (vx * w);
        sy = sy + (vy * w);
    }
    float n = sqrtf((sx * sx) + (sy * sy));
    float d = (n == 0.0f) ? 1.0f : n;
    tdst[idx] = make_float2(sx / d, sy / d);
}

// Stage 3b: H-pass, same structure along y.
__global__ __launch_bounds__(256) void k_etf_h(const float2* __restrict__ tsrc,
                                               float2* __restrict__ tdst,
                                               const float* __restrict__ TH) {
#pragma clang fp contract(off)
    int yi = blockIdx.x * blockDim.x + threadIdx.x;
    int xi = blockIdx.y;
    int b  = blockIdx.z;
    size_t base = (size_t)b * SX * SY;
    size_t rowb = base + (size_t)xi * SY;
    size_t idx  = rowb + yi;

    float2 nt[11];
    float  tv[11];
#pragma unroll
    for (int k = -MU; k <= MU; ++k) {
        int nyc = clampi(yi + k, 0, SY - 1);
        nt[k + MU] = tsrc[rowb + nyc];
        if (k > 0)      tv[k + MU] = TH[(size_t)(k - 1) * NPIX + idx];
        else if (k < 0) tv[k + MU] = TH[(size_t)(-k - 1) * NPIX + rowb + nyc];
        else            tv[k + MU] = 0.0f;
    }
    float2 ct = nt[MU];

    float sx = 0.0f, sy = 0.0f;
#pragma unroll
    for (int k = -MU; k <= MU; ++k) {
        bool valid = ((unsigned)(yi + k)) < (unsigned)SY;
        float2 v = nt[k + MU];
        float vx = valid ? v.x : 0.0f;
        float vy = valid ? v.y : 0.0f;
        float th;
        if (k > 0)      th = valid ?  tv[k + MU] : 0.0f;
        else if (k < 0) th = valid ? -tv[k + MU] : 0.0f;
        else            th = 0.0f;
        float dot = (ct.x * vx) + (ct.y * vy);
        float w   = ((th + 1.0f) * dot) * 0.5f;
        sx = sx + (vx * w);
        sy = sy + (vy * w);
    }
    float n = sqrtf((sx * sx) + (sy * sy));
    float d = (n == 0.0f) ? 1.0f : n;
    tdst[idx] = make_float2(sx / d, sy / d);
}

// Stage 4: DoG (already branchless; 7 gathers in one clause after the e load).
__global__ __launch_bounds__(256) void k_dog(const float* __restrict__ img,
                                             const float2* __restrict__ etf,
                                             float* __restrict__ dog, DogW w) {
#pragma clang fp contract(off)
    int yi = blockIdx.x * blockDim.x + threadIdx.x;
    int xi = blockIdx.y;
    int b  = blockIdx.z;
    size_t base = (size_t)b * SX * SY;
    size_t idx  = base + (size_t)xi * SY + yi;

    float2 e = etf[idx];
    float perx = -e.y;
    float pery =  e.x;
    float xf = (float)xi, yf = (float)yi;

    float il[7];
#pragma unroll
    for (int t = -3; t <= 3; ++t) {
        float tf  = (float)t;
        float ptx = xf + (perx * tf);
        float pty = yf + (pery * tf);
        int px = (int)rintf(fminf(fmaxf(ptx, 0.0f), (float)(SX - 1)));
        int py = (int)rintf(fminf(fmaxf(pty, 0.0f), (float)(SY - 1)));
        il[t + 3] = img[base + (size_t)px * SY + py];
    }
    float acc = 0.0f;
#pragma unroll
    for (int t = -3; t <= 3; ++t) acc = acc + (il[t + 3] * w.g[t + 3]);
    dog[idx] = acc / w.tw;
}

// Stage 5: FDoG dual-chain trace + threshold.
__global__ __launch_bounds__(256) void k_fdog(const float* __restrict__ dog,
                                              const float2* __restrict__ etf,
                                              int* __restrict__ out, FdogW w) {
#pragma clang fp contract(off)
    int yi = blockIdx.x * blockDim.x + threadIdx.x;
    int xi = blockIdx.y;
    int b  = blockIdx.z;
    size_t base = (size_t)b * SX * SY;
    size_t idx  = base + (size_t)xi * SY + yi;

    float d1[9];
    float d2[10];
    float2 e0 = etf[idx];
    float2 e1 = e0, e2 = e0;
    int p1x = xi, p1y = yi;
    int p2x = xi, p2y = yi;
    d2[0] = dog[idx];

#pragma unroll
    for (int s = 1; s <= 9; ++s) {
        float fx1 = (float)p1x + (e1.x * -1.0f);
        float fy1 = (float)p1y + (e1.y * -1.0f);
        p1x = (int)rintf(fminf(fmaxf(fx1, 0.0f), (float)(SX - 1)));
        p1y = (int)rintf(fminf(fmaxf(fy1, 0.0f), (float)(SY - 1)));
        size_t i1 = base + (size_t)p1x * SY + p1y;
        float fx2 = (float)p2x + (e2.x * 1.0f);
        float fy2 = (float)p2y + (e2.y * 1.0f);
        p2x = (int)rintf(fminf(fmaxf(fx2, 0.0f), (float)(SX - 1)));
        p2y = (int)rintf(fminf(fmaxf(fy2, 0.0f), (float)(SY - 1)));
        size_t i2 = base + (size_t)p2x * SY + p2y;

        d1[s - 1] = dog[i1];
        d2[s]     = dog[i2];
        if (s < 9) {
            e1 = etf[i1];
            e2 = etf[i2];
        }
    }

    float acc = 0.0f;
#pragma unroll
    for (int s = 1; s <= 9; ++s) acc = acc + (d1[s - 1] * w.g[s]);
    acc = acc + (d2[0] * w.g[0]);
#pragma unroll
    for (int s = 1; s <= 9; ++s) acc = acc + (d2[s] * w.g[s]);

    float fv = acc / w.tw;
    float th = 1.0f + fast_tanh_f32(fv);
    out[idx] = ((fv < 0.0f) && (th < 0.7f)) ? 0 : 1;
}

static double gpdf(double v, double sig) {
    return exp(-(v * v) / (2.0 * sig * sig)) / (sqrt(2.0 * M_PI) * sig);
}

extern "C" void kernel_launch(void* const* d_in, const int* in_sizes, int n_in,
                              void* d_out, int out_size, void* d_ws, size_t ws_size,
                              hipStream_t stream) {
    const float* img = (const float*)d_in[0];
    int* out = (int*)d_out;
    char* ws = (char*)d_ws;

    // Workspace layout (64 MB + 16 KB + 4 B):
    //   mag [0,4MB) | tA [4,12) | tB [12,20) | TV [20,40) | TH [40,60) | dog [60,64)
    //   partial [64MB, +16KB) | maxbits [+4)
    float*  mag = (float*)(ws);
    float2* tA  = (float2*)(ws + (size_t)4  * MB);
    float2* tB  = (float2*)(ws + (size_t)12 * MB);
    float*  TV  = (float*)(ws + (size_t)20 * MB);
    float*  TH  = (float*)(ws + (size_t)40 * MB);
    float*  dog = (float*)(ws + (size_t)60 * MB);
    float*        partial = (float*)(ws + (size_t)64 * MB);
    unsigned int* maxbits = (unsigned int*)(ws + (size_t)64 * MB + NBLOCKS * sizeof(float));

    DogW dw;
    {
        double tw = 0.0;
        for (int t = -3; t <= 3; ++t) {
            double g = gpdf((double)t, 1.0) - 0.99 * gpdf((double)t, 1.6);
            dw.g[t + 3] = (float)g;
            tw += g;
        }
        dw.tw = (float)tw;
    }
    FdogW fw;
    {
        for (int s = 0; s <= 9; ++s) fw.g[s] = (float)gpdf((double)s, 3.0);
        double tw = 0.0;
        for (int s = 1; s <= 9; ++s) tw += gpdf((double)s, 3.0);
        for (int s = 0; s <= 9; ++s) tw += gpdf((double)s, 3.0);
        fw.tw = (float)tw;
    }

    dim3 blk(256, 1, 1);
    dim3 grd(SY / 256, SX, BN);

    k_sobel<<<grd, blk, 0, stream>>>(img, mag, tA, partial);
    k_reduce<<<1, 256, 0, stream>>>(partial, maxbits);
    k_tanh<<<grd, blk, 0, stream>>>(mag, maxbits, TV, TH);

    float2* src = tA;
    float2* dst = tB;
    for (int it = 0; it < 3; ++it) {
        k_etf_v<<<grd, blk, 0, stream>>>(src, dst, TV);
        { float2* t = src; src = dst; dst = t; }
        k_etf_h<<<grd, blk, 0, stream>>>(src, dst, TH);
        { float2* t = src; src = dst; dst = t; }
    }
    k_dog<<<grd, blk, 0, stream>>>(img, src, dog, dw);
    k_fdog<<<grd, blk, 0, stream>>>(dog, src, out, fw);
}